// Round 5
// baseline (200.723 us; speedup 1.0000x reference)
//
#include <hip/hip_runtime.h>
#include <hip/hip_bf16.h>

typedef __attribute__((ext_vector_type(4))) float f32x4;
typedef __attribute__((ext_vector_type(8))) short bf16x8;
typedef __attribute__((ext_vector_type(4))) int i32x4;

#define SEQ 1024
#define HIDV 768
#define NH 12
#define HD 64
#define QBLK 64

static __device__ __forceinline__ unsigned short f2b(float f) {
  unsigned u = __builtin_bit_cast(unsigned, f);
  u = (u + 0x7fffu + ((u >> 16) & 1u)) >> 16;
  return (unsigned short)u;
}

static __device__ __forceinline__ void gl16(const unsigned short* g, unsigned short* l) {
  __builtin_amdgcn_global_load_lds(
      (const __attribute__((address_space(1))) unsigned int*)g,
      (__attribute__((address_space(3))) unsigned int*)l, 16, 0, 0);
}

// ---------- convert f32 inputs -> bf16 (X, Wq, Wk, Wv, Wo contiguous in ws) ----------
__global__ __launch_bounds__(256) void convert_all(
    const float* __restrict__ X, const float* __restrict__ Wq,
    const float* __restrict__ Wk, const float* __restrict__ Wv,
    const float* __restrict__ Wo, unsigned short* __restrict__ dst) {
  long i = (long)blockIdx.x * 256 + threadIdx.x;
  const long N4 = (3145728L + 4 * 589824L) / 4;
  if (i >= N4) return;
  long e = i * 4;
  const float* src; long off;
  if (e < 3145728L)      { src = X;  off = e; }
  else if (e < 3735552L) { src = Wq; off = e - 3145728L; }
  else if (e < 4325376L) { src = Wk; off = e - 3735552L; }
  else if (e < 4915200L) { src = Wv; off = e - 4325376L; }
  else                   { src = Wo; off = e - 4915200L; }
  const float4 v = *reinterpret_cast<const float4*>(src + off);
  ushort4 o;
  o.x = f2b(v.x); o.y = f2b(v.y); o.z = f2b(v.z); o.w = f2b(v.w);
  *reinterpret_cast<ushort4*>(dst + e) = o;
}

// ---------- fused QKV GEMM: T3-min pipeline (stage-early, dbuf, 1 barrier/step) ----------
__global__ __launch_bounds__(256) void qkv_gemm(
    const unsigned short* __restrict__ Xb,
    const unsigned short* __restrict__ Wqb, const unsigned short* __restrict__ Wkb,
    const unsigned short* __restrict__ Wvb,
    const float* __restrict__ bq, const float* __restrict__ bk, const float* __restrict__ bv,
    unsigned short* __restrict__ Qh, unsigned short* __restrict__ Kh,
    unsigned short* __restrict__ VT) {
  __shared__ __align__(16) unsigned short la[2][128 * 32];
  __shared__ __align__(16) unsigned short lb[2][128 * 32];
  const int z = blockIdx.z;
  const unsigned short* Wb = (z == 0) ? Wqb : (z == 1) ? Wkb : Wvb;
  const float* bias = (z == 0) ? bq : (z == 1) ? bk : bv;
  const int m0 = blockIdx.x * 128, n0 = blockIdx.y * 128;
  const int tid = threadIdx.x;
  const int wave = tid >> 6, lane = tid & 63, g = lane >> 4, c = lane & 15;
  const int wr = (wave >> 1) * 64, wc = (wave & 1) * 64;

  const int sr = wave * 16 + (lane >> 2);
  const int scol = (lane & 3) * 8;
  const unsigned short* Ag = &Xb[(size_t)(m0 + sr) * HIDV + scol];
  const unsigned short* Bg = &Wb[(size_t)(n0 + sr) * HIDV + scol];

  // prologue: stage k-step 0 into buf 0
  gl16(Ag, &la[0][(wave * 16) * 32]);
  gl16(Ag + (size_t)64 * HIDV, &la[0][(64 + wave * 16) * 32]);
  gl16(Bg, &lb[0][(wave * 16) * 32]);
  gl16(Bg + (size_t)64 * HIDV, &lb[0][(64 + wave * 16) * 32]);
  __syncthreads();

  f32x4 acc[4][4] = {};
  for (int t = 0; t < 24; t++) {
    const int cur = t & 1;
    if (t < 23) {
      const int kt = (t + 1) * 32;
      gl16(Ag + kt, &la[cur ^ 1][(wave * 16) * 32]);
      gl16(Ag + (size_t)64 * HIDV + kt, &la[cur ^ 1][(64 + wave * 16) * 32]);
      gl16(Bg + kt, &lb[cur ^ 1][(wave * 16) * 32]);
      gl16(Bg + (size_t)64 * HIDV + kt, &lb[cur ^ 1][(64 + wave * 16) * 32]);
    }
    bf16x8 af[4], bfr[4];
#pragma unroll
    for (int m = 0; m < 4; m++)
      af[m] = *reinterpret_cast<bf16x8*>(&la[cur][(wr + m * 16 + c) * 32 + g * 8]);
#pragma unroll
    for (int n = 0; n < 4; n++)
      bfr[n] = *reinterpret_cast<bf16x8*>(&lb[cur][(wc + n * 16 + c) * 32 + g * 8]);
#pragma unroll
    for (int m = 0; m < 4; m++)
#pragma unroll
      for (int n = 0; n < 4; n++)
        acc[m][n] = __builtin_amdgcn_mfma_f32_16x16x32_bf16(af[m], bfr[n], acc[m][n], 0, 0, 0);
    __syncthreads();  // drains vmcnt: next buf staged; WAR on cur buf cleared
  }
  float bv4[4];
#pragma unroll
  for (int n = 0; n < 4; n++) bv4[n] = bias[n0 + wc + n * 16 + c];
  if (z < 2) {
    unsigned short* dst = (z == 0) ? Qh : Kh;
#pragma unroll
    for (int m = 0; m < 4; m++) {
      int rb_ = m0 + wr + m * 16 + g * 4;
#pragma unroll
      for (int n = 0; n < 4; n++) {
        int col = n0 + wc + n * 16 + c;
        int h = col >> 6, d = col & 63;
#pragma unroll
        for (int r = 0; r < 4; r++) {
          int row = rb_ + r;
          int b = row >> 10, s = row & 1023;
          dst[((size_t)(b * NH + h) * SEQ + s) * HD + d] = f2b(acc[m][n][r] + bv4[n]);
        }
      }
    }
  } else {
#pragma unroll
    for (int m = 0; m < 4; m++) {
      int rb_ = m0 + wr + m * 16 + g * 4;
      int b = rb_ >> 10, s = rb_ & 1023;
#pragma unroll
      for (int n = 0; n < 4; n++) {
        int col = n0 + wc + n * 16 + c;
        int h = col >> 6, d = col & 63;
        ushort4 o;
        o.x = f2b(acc[m][n][0] + bv4[n]);
        o.y = f2b(acc[m][n][1] + bv4[n]);
        o.z = f2b(acc[m][n][2] + bv4[n]);
        o.w = f2b(acc[m][n][3] + bv4[n]);
        *reinterpret_cast<ushort4*>(&VT[((size_t)(b * NH + h) * HD + d) * SEQ + s]) = o;
      }
    }
  }
}

// ---------- fused attention: zero barriers, no K/V staging (L1/L2-resident) ----------
// Each wave is fully independent: owns 16 q-rows, sweeps all k with direct
// global fragment loads; lp is a per-wave LDS region (P bf16 round-trip only).
#define EXPC 0.18033688f  /* 0.125 * log2(e) */
__global__ __launch_bounds__(256) void attn_fused(
    const unsigned short* __restrict__ Qh, const unsigned short* __restrict__ Kh,
    const unsigned short* __restrict__ VT,
    float* __restrict__ probs, unsigned short* __restrict__ CTX) {
  __shared__ __align__(16) unsigned short lp[4][16 * 72];
  const int bh = blockIdx.y, rb = blockIdx.x * QBLK;
  const int b = bh / NH, h = bh - b * NH;
  const unsigned short* Qp = Qh + (size_t)bh * SEQ * HD;
  const unsigned short* Kp = Kh + (size_t)bh * SEQ * HD;
  const unsigned short* Vp = VT + (size_t)bh * HD * SEQ;
  float* P = probs + (size_t)bh * SEQ * SEQ;
  const int tid = threadIdx.x, wave = tid >> 6, lane = tid & 63, g = lane >> 4, c = lane & 15;
  const int qrow = rb + wave * 16 + c;   // this lane's q row
  unsigned short* myp = &lp[wave][0];    // [16 q][72]

  // Q fragments (B-operand) straight from global
  bf16x8 aq[2];
#pragma unroll
  for (int ks = 0; ks < 2; ks++)
    aq[ks] = *reinterpret_cast<const bf16x8*>(&Qp[(size_t)qrow * HD + ks * 32 + g * 8]);

  // ---- sweep 1: row sums, no barriers, no LDS ----
  float lsum = 0.f;
  for (int ct = 0; ct < 16; ct++) {
    f32x4 sreg[4] = {};
#pragma unroll
    for (int ks = 0; ks < 2; ks++) {
      bf16x8 kf[4];
#pragma unroll
      for (int kb = 0; kb < 4; kb++)
        kf[kb] = *reinterpret_cast<const bf16x8*>(
            &Kp[(size_t)(ct * 64 + kb * 16 + c) * HD + ks * 32 + g * 8]);
#pragma unroll
      for (int kb = 0; kb < 4; kb++)
        sreg[kb] = __builtin_amdgcn_mfma_f32_16x16x32_bf16(kf[kb], aq[ks], sreg[kb], 0, 0, 0);
    }
#pragma unroll
    for (int kb = 0; kb < 4; kb++)
#pragma unroll
      for (int r = 0; r < 4; r++)
        lsum += __builtin_amdgcn_exp2f(sreg[kb][r] * EXPC);
  }
  float s = lsum;
  s += __shfl_xor(s, 16);
  s += __shfl_xor(s, 32);
  const float linv = 1.f / s;

  // ---- sweep 2: probs write + PV, no barriers ----
  f32x4 acc[4] = {};
  for (int ct = 0; ct < 16; ct++) {
    f32x4 sreg[4] = {};
#pragma unroll
    for (int ks = 0; ks < 2; ks++) {
      bf16x8 kf[4];
#pragma unroll
      for (int kb = 0; kb < 4; kb++)
        kf[kb] = *reinterpret_cast<const bf16x8*>(
            &Kp[(size_t)(ct * 64 + kb * 16 + c) * HD + ks * 32 + g * 8]);
#pragma unroll
      for (int kb = 0; kb < 4; kb++)
        sreg[kb] = __builtin_amdgcn_mfma_f32_16x16x32_bf16(kf[kb], aq[ks], sreg[kb], 0, 0, 0);
    }
    {
      float* Prow = &P[(size_t)qrow * SEQ + ct * 64];
#pragma unroll
      for (int kb = 0; kb < 4; kb++) {
        f32x4 p;
#pragma unroll
        for (int r = 0; r < 4; r++)
          p[r] = __builtin_amdgcn_exp2f(sreg[kb][r] * EXPC) * linv;
        *reinterpret_cast<f32x4*>(&Prow[kb * 16 + g * 4]) = p;
        uint2 pk;
        pk.x = (unsigned)f2b(p[0]) | ((unsigned)f2b(p[1]) << 16);
        pk.y = (unsigned)f2b(p[2]) | ((unsigned)f2b(p[3]) << 16);
        *reinterpret_cast<uint2*>(&myp[c * 72 + kb * 16 + g * 4]) = pk;
      }
    }
    // PV: pa from per-wave lp (compiler orders ds_write->ds_read), vf direct global
#pragma unroll
    for (int ks = 0; ks < 2; ks++) {
      bf16x8 pa, vf[4];
      pa = *reinterpret_cast<bf16x8*>(&myp[c * 72 + ks * 32 + g * 8]);
#pragma unroll
      for (int db = 0; db < 4; db++)
        vf[db] = *reinterpret_cast<const bf16x8*>(
            &Vp[(size_t)(db * 16 + c) * SEQ + ct * 64 + ks * 32 + g * 8]);
#pragma unroll
      for (int db = 0; db < 4; db++)
        acc[db] = __builtin_amdgcn_mfma_f32_16x16x32_bf16(pa, vf[db], acc[db], 0, 0, 0);
    }
  }

  // ---- CTX epilogue: per-wave LDS bounce, coalesced 16B stores ----
#pragma unroll
  for (int db = 0; db < 4; db++)
#pragma unroll
    for (int r = 0; r < 4; r++)
      myp[(g * 4 + r) * 72 + db * 16 + c] = f2b(acc[db][r]);
  {
    const int q = lane >> 2, seg = (lane & 3) * 16;
    const unsigned short* src = &myp[q * 72 + seg];
    unsigned short* dst = &CTX[(size_t)(b * SEQ + rb + wave * 16 + q) * HIDV + h * HD + seg];
    i32x4 t0 = *reinterpret_cast<const i32x4*>(&src[0]);
    i32x4 t1 = *reinterpret_cast<const i32x4*>(&src[8]);
    *reinterpret_cast<i32x4*>(&dst[0]) = t0;
    *reinterpret_cast<i32x4*>(&dst[8]) = t1;
  }
}

// ---------- output projection: T3-min pipeline ----------
__global__ __launch_bounds__(256) void proj_gemm(
    const unsigned short* __restrict__ Ab, const unsigned short* __restrict__ Wb,
    const float* __restrict__ bias, float* __restrict__ out) {
  __shared__ __align__(16) unsigned short la[2][128 * 32];
  __shared__ __align__(16) unsigned short lb[2][128 * 32];
  const int m0 = blockIdx.x * 128, n0 = blockIdx.y * 128;
  const int tid = threadIdx.x;
  const int wave = tid >> 6, lane = tid & 63, g = lane >> 4, c = lane & 15;
  const int wr = (wave >> 1) * 64, wc = (wave & 1) * 64;
  const int sr = wave * 16 + (lane >> 2);
  const int scol = (lane & 3) * 8;
  const unsigned short* Ag = &Ab[(size_t)(m0 + sr) * HIDV + scol];
  const unsigned short* Bg = &Wb[(size_t)(n0 + sr) * HIDV + scol];

  gl16(Ag, &la[0][(wave * 16) * 32]);
  gl16(Ag + (size_t)64 * HIDV, &la[0][(64 + wave * 16) * 32]);
  gl16(Bg, &lb[0][(wave * 16) * 32]);
  gl16(Bg + (size_t)64 * HIDV, &lb[0][(64 + wave * 16) * 32]);
  __syncthreads();

  f32x4 acc[4][4] = {};
  for (int t = 0; t < 24; t++) {
    const int cur = t & 1;
    if (t < 23) {
      const int kt = (t + 1) * 32;
      gl16(Ag + kt, &la[cur ^ 1][(wave * 16) * 32]);
      gl16(Ag + (size_t)64 * HIDV + kt, &la[cur ^ 1][(64 + wave * 16) * 32]);
      gl16(Bg + kt, &lb[cur ^ 1][(wave * 16) * 32]);
      gl16(Bg + (size_t)64 * HIDV + kt, &lb[cur ^ 1][(64 + wave * 16) * 32]);
    }
    bf16x8 af[4], bfr[4];
#pragma unroll
    for (int m = 0; m < 4; m++)
      af[m] = *reinterpret_cast<bf16x8*>(&la[cur][(wr + m * 16 + c) * 32 + g * 8]);
#pragma unroll
    for (int n = 0; n < 4; n++)
      bfr[n] = *reinterpret_cast<bf16x8*>(&lb[cur][(wc + n * 16 + c) * 32 + g * 8]);
#pragma unroll
    for (int m = 0; m < 4; m++)
#pragma unroll
      for (int n = 0; n < 4; n++)
        acc[m][n] = __builtin_amdgcn_mfma_f32_16x16x32_bf16(af[m], bfr[n], acc[m][n], 0, 0, 0);
    __syncthreads();
  }
  float bv4[4];
#pragma unroll
  for (int n = 0; n < 4; n++) bv4[n] = bias[n0 + wc + n * 16 + c];
#pragma unroll
  for (int m = 0; m < 4; m++) {
    int rb_ = m0 + wr + m * 16 + g * 4;
#pragma unroll
    for (int n = 0; n < 4; n++) {
      int col = n0 + wc + n * 16 + c;
#pragma unroll
      for (int r = 0; r < 4; r++)
        out[(size_t)(rb_ + r) * HIDV + col] = acc[m][n][r] + bv4[n];
    }
  }
}

extern "C" void kernel_launch(void* const* d_in, const int* in_sizes, int n_in,
                              void* d_out, int out_size, void* d_ws, size_t ws_size,
                              hipStream_t stream) {
  const float* X  = (const float*)d_in[0];
  const float* Wq = (const float*)d_in[1];
  const float* bq = (const float*)d_in[2];
  const float* Wk = (const float*)d_in[3];
  const float* bk = (const float*)d_in[4];
  const float* Wv = (const float*)d_in[5];
  const float* bv = (const float*)d_in[6];
  const float* Wo = (const float*)d_in[7];
  const float* bo = (const float*)d_in[8];
  float* out = (float*)d_out;
  float* probs = out + 3145728;  // output 1 region

  unsigned short* Xb  = (unsigned short*)d_ws;        // [4096,768]
  unsigned short* Wqb = Xb + 3145728;                 // [768,768]
  unsigned short* Wkb = Wqb + 589824;
  unsigned short* Wvb = Wkb + 589824;
  unsigned short* Wob = Wvb + 589824;
  unsigned short* Qh  = Wob + 589824;                 // [4,12,1024,64]
  unsigned short* Kh  = Qh + 3145728;
  unsigned short* VT  = Kh + 3145728;                 // [4,12,64,1024]
  unsigned short* CTX = VT + 3145728;                 // [4096,768]

  convert_all<<<5376, 256, 0, stream>>>(X, Wq, Wk, Wv, Wo, Xb);
  qkv_gemm<<<dim3(32, 6, 3), 256, 0, stream>>>(Xb, Wqb, Wkb, Wvb, bq, bk, bv, Qh, Kh, VT);
  attn_fused<<<dim3(16, 48), 256, 0, stream>>>(Qh, Kh, VT, probs, CTX);
  proj_gemm<<<dim3(32, 6), 256, 0, stream>>>(CTX, Wob, bo, out);
}

// Round 6
// 113.360 us; speedup vs baseline: 1.7707x; 1.7707x over previous
//
#include <hip/hip_runtime.h>
#include <hip/hip_bf16.h>

typedef __attribute__((ext_vector_type(4))) float f32x4;
typedef __attribute__((ext_vector_type(8))) short bf16x8;
typedef __attribute__((ext_vector_type(4))) int i32x4;

#define SEQ 1024
#define HIDV 768
#define NH 12
#define HD 64
#define QBLK 64

static __device__ __forceinline__ unsigned short f2b(float f) {
  unsigned u = __builtin_bit_cast(unsigned, f);
  u = (u + 0x7fffu + ((u >> 16) & 1u)) >> 16;
  return (unsigned short)u;
}

static __device__ __forceinline__ void gl16(const unsigned short* g, unsigned short* l) {
  __builtin_amdgcn_global_load_lds(
      (const __attribute__((address_space(1))) unsigned int*)g,
      (__attribute__((address_space(3))) unsigned int*)l, 16, 0, 0);
}

// barrier that waits ONLY on LDS ops (keeps global stores in flight)
static __device__ __forceinline__ void bar_lgkm() {
  asm volatile("s_waitcnt lgkmcnt(0)" ::: "memory");
  __builtin_amdgcn_sched_barrier(0);
  __builtin_amdgcn_s_barrier();
  __builtin_amdgcn_sched_barrier(0);
}
// rendezvous-only barrier (all per-wave LDS reads already consumed)
static __device__ __forceinline__ void bar_only() {
  __builtin_amdgcn_sched_barrier(0);
  __builtin_amdgcn_s_barrier();
  __builtin_amdgcn_sched_barrier(0);
}

// ---------- convert f32 inputs -> bf16 (X, Wq, Wk, Wv, Wo contiguous in ws) ----------
__global__ __launch_bounds__(256) void convert_all(
    const float* __restrict__ X, const float* __restrict__ Wq,
    const float* __restrict__ Wk, const float* __restrict__ Wv,
    const float* __restrict__ Wo, unsigned short* __restrict__ dst) {
  long i = (long)blockIdx.x * 256 + threadIdx.x;
  const long N4 = (3145728L + 4 * 589824L) / 4;
  if (i >= N4) return;
  long e = i * 4;
  const float* src; long off;
  if (e < 3145728L)      { src = X;  off = e; }
  else if (e < 3735552L) { src = Wq; off = e - 3145728L; }
  else if (e < 4325376L) { src = Wk; off = e - 3735552L; }
  else if (e < 4915200L) { src = Wv; off = e - 4325376L; }
  else                   { src = Wo; off = e - 4915200L; }
  const float4 v = *reinterpret_cast<const float4*>(src + off);
  ushort4 o;
  o.x = f2b(v.x); o.y = f2b(v.y); o.z = f2b(v.z); o.w = f2b(v.w);
  *reinterpret_cast<ushort4*>(dst + e) = o;
}

// ---------- fused QKV GEMM: T3-min pipeline (stage-early, dbuf, 1 barrier/step) ----------
__global__ __launch_bounds__(256) void qkv_gemm(
    const unsigned short* __restrict__ Xb,
    const unsigned short* __restrict__ Wqb, const unsigned short* __restrict__ Wkb,
    const unsigned short* __restrict__ Wvb,
    const float* __restrict__ bq, const float* __restrict__ bk, const float* __restrict__ bv,
    unsigned short* __restrict__ Qh, unsigned short* __restrict__ Kh,
    unsigned short* __restrict__ VT) {
  __shared__ __align__(16) unsigned short la[2][128 * 32];
  __shared__ __align__(16) unsigned short lb[2][128 * 32];
  const int z = blockIdx.z;
  const unsigned short* Wb = (z == 0) ? Wqb : (z == 1) ? Wkb : Wvb;
  const float* bias = (z == 0) ? bq : (z == 1) ? bk : bv;
  const int m0 = blockIdx.x * 128, n0 = blockIdx.y * 128;
  const int tid = threadIdx.x;
  const int wave = tid >> 6, lane = tid & 63, g = lane >> 4, c = lane & 15;
  const int wr = (wave >> 1) * 64, wc = (wave & 1) * 64;

  const int sr = wave * 16 + (lane >> 2);
  const int scol = (lane & 3) * 8;
  const unsigned short* Ag = &Xb[(size_t)(m0 + sr) * HIDV + scol];
  const unsigned short* Bg = &Wb[(size_t)(n0 + sr) * HIDV + scol];

  gl16(Ag, &la[0][(wave * 16) * 32]);
  gl16(Ag + (size_t)64 * HIDV, &la[0][(64 + wave * 16) * 32]);
  gl16(Bg, &lb[0][(wave * 16) * 32]);
  gl16(Bg + (size_t)64 * HIDV, &lb[0][(64 + wave * 16) * 32]);
  __syncthreads();

  f32x4 acc[4][4] = {};
  for (int t = 0; t < 24; t++) {
    const int cur = t & 1;
    if (t < 23) {
      const int kt = (t + 1) * 32;
      gl16(Ag + kt, &la[cur ^ 1][(wave * 16) * 32]);
      gl16(Ag + (size_t)64 * HIDV + kt, &la[cur ^ 1][(64 + wave * 16) * 32]);
      gl16(Bg + kt, &lb[cur ^ 1][(wave * 16) * 32]);
      gl16(Bg + (size_t)64 * HIDV + kt, &lb[cur ^ 1][(64 + wave * 16) * 32]);
    }
    bf16x8 af[4], bfr[4];
#pragma unroll
    for (int m = 0; m < 4; m++)
      af[m] = *reinterpret_cast<bf16x8*>(&la[cur][(wr + m * 16 + c) * 32 + g * 8]);
#pragma unroll
    for (int n = 0; n < 4; n++)
      bfr[n] = *reinterpret_cast<bf16x8*>(&lb[cur][(wc + n * 16 + c) * 32 + g * 8]);
#pragma unroll
    for (int m = 0; m < 4; m++)
#pragma unroll
      for (int n = 0; n < 4; n++)
        acc[m][n] = __builtin_amdgcn_mfma_f32_16x16x32_bf16(af[m], bfr[n], acc[m][n], 0, 0, 0);
    __syncthreads();
  }
  float bv4[4];
#pragma unroll
  for (int n = 0; n < 4; n++) bv4[n] = bias[n0 + wc + n * 16 + c];
  if (z < 2) {
    unsigned short* dst = (z == 0) ? Qh : Kh;
#pragma unroll
    for (int m = 0; m < 4; m++) {
      int rb_ = m0 + wr + m * 16 + g * 4;
#pragma unroll
      for (int n = 0; n < 4; n++) {
        int col = n0 + wc + n * 16 + c;
        int h = col >> 6, d = col & 63;
#pragma unroll
        for (int r = 0; r < 4; r++) {
          int row = rb_ + r;
          int b = row >> 10, s = row & 1023;
          dst[((size_t)(b * NH + h) * SEQ + s) * HD + d] = f2b(acc[m][n][r] + bv4[n]);
        }
      }
    }
  } else {
#pragma unroll
    for (int m = 0; m < 4; m++) {
      int rb_ = m0 + wr + m * 16 + g * 4;
      int b = rb_ >> 10, s = rb_ & 1023;
#pragma unroll
      for (int n = 0; n < 4; n++) {
        int col = n0 + wc + n * 16 + c;
        int h = col >> 6, d = col & 63;
        ushort4 o;
        o.x = f2b(acc[m][n][0] + bv4[n]);
        o.y = f2b(acc[m][n][1] + bv4[n]);
        o.z = f2b(acc[m][n][2] + bv4[n]);
        o.w = f2b(acc[m][n][3] + bv4[n]);
        *reinterpret_cast<ushort4*>(&VT[((size_t)(b * NH + h) * HD + d) * SEQ + s]) = o;
      }
    }
  }
}

// ---------- fused attention (round-4 structure + XCD-aware block swizzle) ----------
#define EXPC 0.18033688f  /* 0.125 * log2(e) */
__global__ __launch_bounds__(256) void attn_fused(
    const unsigned short* __restrict__ Qh, const unsigned short* __restrict__ Kh,
    const unsigned short* __restrict__ VT,
    float* __restrict__ probs, unsigned short* __restrict__ CTX) {
  __shared__ __align__(16) unsigned short ldsk[2][64 * 72];
  __shared__ __align__(16) unsigned short ldsv[2][64 * 72];
  __shared__ __align__(16) unsigned short lp[64 * 72];
  // XCD swizzle: 768 blocks, 8 XCDs -> each XCD owns 96 consecutive lin ids
  // = 6 consecutive heads (K/V 1.5 MB per XCD -> per-XCD L2 resident).
  const int lin = blockIdx.x;
  const int swz = (lin & 7) * 96 + (lin >> 3);
  const int bh = swz >> 4, rb = (swz & 15) * QBLK;
  const int b = bh / NH, h = bh - b * NH;
  const unsigned short* Qp = Qh + (size_t)bh * SEQ * HD;
  const unsigned short* Kp = Kh + (size_t)bh * SEQ * HD;
  const unsigned short* Vp = VT + (size_t)bh * HD * SEQ;
  float* P = probs + (size_t)bh * SEQ * SEQ;
  const int tid = threadIdx.x, wave = tid >> 6, lane = tid & 63, g = lane >> 4, c = lane & 15;
  const int wrow = wave * 16;
  const int str = tid >> 3;         // 0..31 staging row
  const int stc = (tid & 7) * 8;    // staging col (bf16 elems)

  // Q fragments straight from global (L2-resident): B-operand, q = wrow + c
  bf16x8 aq[2];
#pragma unroll
  for (int ks = 0; ks < 2; ks++)
    aq[ks] = *reinterpret_cast<const bf16x8*>(&Qp[(size_t)(rb + wrow + c) * HD + ks * 32 + g * 8]);

  i32x4 kr0, kr1, vr0, vr1;
  // stage K tile 0
  kr0 = *reinterpret_cast<const i32x4*>(&Kp[(size_t)str * HD + stc]);
  kr1 = *reinterpret_cast<const i32x4*>(&Kp[(size_t)(str + 32) * HD + stc]);
  *reinterpret_cast<i32x4*>(&ldsk[0][str * 72 + stc]) = kr0;
  *reinterpret_cast<i32x4*>(&ldsk[0][(str + 32) * 72 + stc]) = kr1;
  bar_lgkm();

  // ---- sweep 1: row sums (lane-local accumulation, 1 cheap barrier/tile) ----
  float lsum = 0.f;
  for (int ct = 0; ct < 16; ct++) {
    const int cur = ct & 1;
    if (ct < 15) {
      kr0 = *reinterpret_cast<const i32x4*>(&Kp[(size_t)((ct + 1) * 64 + str) * HD + stc]);
      kr1 = *reinterpret_cast<const i32x4*>(&Kp[(size_t)((ct + 1) * 64 + str + 32) * HD + stc]);
    }
    f32x4 sreg[4] = {};
#pragma unroll
    for (int ks = 0; ks < 2; ks++) {
      bf16x8 kf[4];
#pragma unroll
      for (int kb = 0; kb < 4; kb++)
        kf[kb] = *reinterpret_cast<bf16x8*>(&ldsk[cur][(kb * 16 + c) * 72 + ks * 32 + g * 8]);
#pragma unroll
      for (int kb = 0; kb < 4; kb++)
        sreg[kb] = __builtin_amdgcn_mfma_f32_16x16x32_bf16(kf[kb], aq[ks], sreg[kb], 0, 0, 0);
    }
#pragma unroll
    for (int kb = 0; kb < 4; kb++)
#pragma unroll
      for (int r = 0; r < 4; r++)
        lsum += __builtin_amdgcn_exp2f(sreg[kb][r] * EXPC);
    if (ct < 15) {
      *reinterpret_cast<i32x4*>(&ldsk[cur ^ 1][str * 72 + stc]) = kr0;
      *reinterpret_cast<i32x4*>(&ldsk[cur ^ 1][(str + 32) * 72 + stc]) = kr1;
      bar_lgkm();
    }
  }
  float s = lsum;
  s += __shfl_xor(s, 16);
  s += __shfl_xor(s, 32);
  const float linv = 1.f / s;

  // ---- sweep 2 prologue: stage K0 + V0 ----
  kr0 = *reinterpret_cast<const i32x4*>(&Kp[(size_t)str * HD + stc]);
  kr1 = *reinterpret_cast<const i32x4*>(&Kp[(size_t)(str + 32) * HD + stc]);
  vr0 = *reinterpret_cast<const i32x4*>(&Vp[(size_t)str * SEQ + stc]);
  vr1 = *reinterpret_cast<const i32x4*>(&Vp[(size_t)(str + 32) * SEQ + stc]);
  *reinterpret_cast<i32x4*>(&ldsk[0][str * 72 + stc]) = kr0;
  *reinterpret_cast<i32x4*>(&ldsk[0][(str + 32) * 72 + stc]) = kr1;
  *reinterpret_cast<i32x4*>(&ldsv[0][str * 72 + stc]) = vr0;
  *reinterpret_cast<i32x4*>(&ldsv[0][(str + 32) * 72 + stc]) = vr1;
  bar_lgkm();

  // ---- sweep 2: probs write (stores ride across barriers) + PV ----
  f32x4 acc[4] = {};
  for (int ct = 0; ct < 16; ct++) {
    const int cur = ct & 1;
    if (ct < 15) {
      kr0 = *reinterpret_cast<const i32x4*>(&Kp[(size_t)((ct + 1) * 64 + str) * HD + stc]);
      kr1 = *reinterpret_cast<const i32x4*>(&Kp[(size_t)((ct + 1) * 64 + str + 32) * HD + stc]);
      vr0 = *reinterpret_cast<const i32x4*>(&Vp[(size_t)str * SEQ + (ct + 1) * 64 + stc]);
      vr1 = *reinterpret_cast<const i32x4*>(&Vp[(size_t)(str + 32) * SEQ + (ct + 1) * 64 + stc]);
    }
    f32x4 sreg[4] = {};
#pragma unroll
    for (int ks = 0; ks < 2; ks++) {
      bf16x8 kf[4];
#pragma unroll
      for (int kb = 0; kb < 4; kb++)
        kf[kb] = *reinterpret_cast<bf16x8*>(&ldsk[cur][(kb * 16 + c) * 72 + ks * 32 + g * 8]);
#pragma unroll
      for (int kb = 0; kb < 4; kb++)
        sreg[kb] = __builtin_amdgcn_mfma_f32_16x16x32_bf16(kf[kb], aq[ks], sreg[kb], 0, 0, 0);
    }
    {
      float* Prow = &P[(size_t)(rb + wrow + c) * SEQ + ct * 64];
#pragma unroll
      for (int kb = 0; kb < 4; kb++) {
        f32x4 p;
#pragma unroll
        for (int r = 0; r < 4; r++)
          p[r] = __builtin_amdgcn_exp2f(sreg[kb][r] * EXPC) * linv;
        *reinterpret_cast<f32x4*>(&Prow[kb * 16 + g * 4]) = p;
        uint2 pk;
        pk.x = (unsigned)f2b(p[0]) | ((unsigned)f2b(p[1]) << 16);
        pk.y = (unsigned)f2b(p[2]) | ((unsigned)f2b(p[3]) << 16);
        *reinterpret_cast<uint2*>(&lp[(wrow + c) * 72 + kb * 16 + g * 4]) = pk;
      }
    }
    if (ct < 15) {
      *reinterpret_cast<i32x4*>(&ldsk[cur ^ 1][str * 72 + stc]) = kr0;
      *reinterpret_cast<i32x4*>(&ldsk[cur ^ 1][(str + 32) * 72 + stc]) = kr1;
      *reinterpret_cast<i32x4*>(&ldsv[cur ^ 1][str * 72 + stc]) = vr0;
      *reinterpret_cast<i32x4*>(&ldsv[cur ^ 1][(str + 32) * 72 + stc]) = vr1;
    }
    bar_lgkm();  // A: lp + staged tiles visible; P-stores stay in flight
#pragma unroll
    for (int ks = 0; ks < 2; ks++) {
      bf16x8 pa, vf[4];
      pa = *reinterpret_cast<bf16x8*>(&lp[(wrow + c) * 72 + ks * 32 + g * 8]);
#pragma unroll
      for (int db = 0; db < 4; db++)
        vf[db] = *reinterpret_cast<bf16x8*>(&ldsv[cur][(db * 16 + c) * 72 + ks * 32 + g * 8]);
#pragma unroll
      for (int db = 0; db < 4; db++)
        acc[db] = __builtin_amdgcn_mfma_f32_16x16x32_bf16(pa, vf[db], acc[db], 0, 0, 0);
    }
    bar_only();  // B: PV reads consumed before next tile's lp/ldsv writes
  }

  // ---- CTX epilogue: bounce through lp for coalesced 16B stores ----
#pragma unroll
  for (int db = 0; db < 4; db++)
#pragma unroll
    for (int r = 0; r < 4; r++)
      lp[(wrow + g * 4 + r) * 72 + db * 16 + c] = f2b(acc[db][r]);
  bar_lgkm();
  {
    const int q = tid >> 2, seg = (tid & 3) * 16;
    const unsigned short* src = &lp[q * 72 + seg];
    unsigned short* dst = &CTX[(size_t)(b * SEQ + rb + q) * HIDV + h * HD + seg];
    i32x4 t0 = *reinterpret_cast<const i32x4*>(&src[0]);
    i32x4 t1 = *reinterpret_cast<const i32x4*>(&src[8]);
    *reinterpret_cast<i32x4*>(&dst[0]) = t0;
    *reinterpret_cast<i32x4*>(&dst[8]) = t1;
  }
}

// ---------- output projection: T3-min pipeline ----------
__global__ __launch_bounds__(256) void proj_gemm(
    const unsigned short* __restrict__ Ab, const unsigned short* __restrict__ Wb,
    const float* __restrict__ bias, float* __restrict__ out) {
  __shared__ __align__(16) unsigned short la[2][128 * 32];
  __shared__ __align__(16) unsigned short lb[2][128 * 32];
  const int m0 = blockIdx.x * 128, n0 = blockIdx.y * 128;
  const int tid = threadIdx.x;
  const int wave = tid >> 6, lane = tid & 63, g = lane >> 4, c = lane & 15;
  const int wr = (wave >> 1) * 64, wc = (wave & 1) * 64;
  const int sr = wave * 16 + (lane >> 2);
  const int scol = (lane & 3) * 8;
  const unsigned short* Ag = &Ab[(size_t)(m0 + sr) * HIDV + scol];
  const unsigned short* Bg = &Wb[(size_t)(n0 + sr) * HIDV + scol];

  gl16(Ag, &la[0][(wave * 16) * 32]);
  gl16(Ag + (size_t)64 * HIDV, &la[0][(64 + wave * 16) * 32]);
  gl16(Bg, &lb[0][(wave * 16) * 32]);
  gl16(Bg + (size_t)64 * HIDV, &lb[0][(64 + wave * 16) * 32]);
  __syncthreads();

  f32x4 acc[4][4] = {};
  for (int t = 0; t < 24; t++) {
    const int cur = t & 1;
    if (t < 23) {
      const int kt = (t + 1) * 32;
      gl16(Ag + kt, &la[cur ^ 1][(wave * 16) * 32]);
      gl16(Ag + (size_t)64 * HIDV + kt, &la[cur ^ 1][(64 + wave * 16) * 32]);
      gl16(Bg + kt, &lb[cur ^ 1][(wave * 16) * 32]);
      gl16(Bg + (size_t)64 * HIDV + kt, &lb[cur ^ 1][(64 + wave * 16) * 32]);
    }
    bf16x8 af[4], bfr[4];
#pragma unroll
    for (int m = 0; m < 4; m++)
      af[m] = *reinterpret_cast<bf16x8*>(&la[cur][(wr + m * 16 + c) * 32 + g * 8]);
#pragma unroll
    for (int n = 0; n < 4; n++)
      bfr[n] = *reinterpret_cast<bf16x8*>(&lb[cur][(wc + n * 16 + c) * 32 + g * 8]);
#pragma unroll
    for (int m = 0; m < 4; m++)
#pragma unroll
      for (int n = 0; n < 4; n++)
        acc[m][n] = __builtin_amdgcn_mfma_f32_16x16x32_bf16(af[m], bfr[n], acc[m][n], 0, 0, 0);
    __syncthreads();
  }
  float bv4[4];
#pragma unroll
  for (int n = 0; n < 4; n++) bv4[n] = bias[n0 + wc + n * 16 + c];
#pragma unroll
  for (int m = 0; m < 4; m++) {
    int rb_ = m0 + wr + m * 16 + g * 4;
#pragma unroll
    for (int n = 0; n < 4; n++) {
      int col = n0 + wc + n * 16 + c;
#pragma unroll
      for (int r = 0; r < 4; r++)
        out[(size_t)(rb_ + r) * HIDV + col] = acc[m][n][r] + bv4[n];
    }
  }
}

extern "C" void kernel_launch(void* const* d_in, const int* in_sizes, int n_in,
                              void* d_out, int out_size, void* d_ws, size_t ws_size,
                              hipStream_t stream) {
  const float* X  = (const float*)d_in[0];
  const float* Wq = (const float*)d_in[1];
  const float* bq = (const float*)d_in[2];
  const float* Wk = (const float*)d_in[3];
  const float* bk = (const float*)d_in[4];
  const float* Wv = (const float*)d_in[5];
  const float* bv = (const float*)d_in[6];
  const float* Wo = (const float*)d_in[7];
  const float* bo = (const float*)d_in[8];
  float* out = (float*)d_out;
  float* probs = out + 3145728;  // output 1 region

  unsigned short* Xb  = (unsigned short*)d_ws;        // [4096,768]
  unsigned short* Wqb = Xb + 3145728;                 // [768,768]
  unsigned short* Wkb = Wqb + 589824;
  unsigned short* Wvb = Wkb + 589824;
  unsigned short* Wob = Wvb + 589824;
  unsigned short* Qh  = Wob + 589824;                 // [4,12,1024,64]
  unsigned short* Kh  = Qh + 3145728;
  unsigned short* VT  = Kh + 3145728;                 // [4,12,64,1024]
  unsigned short* CTX = VT + 3145728;                 // [4096,768]

  convert_all<<<5376, 256, 0, stream>>>(X, Wq, Wk, Wv, Wo, Xb);
  qkv_gemm<<<dim3(32, 6, 3), 256, 0, stream>>>(Xb, Wqb, Wkb, Wvb, bq, bk, bv, Qh, Kh, VT);
  attn_fused<<<dim3(768), 256, 0, stream>>>(Qh, Kh, VT, probs, CTX);
  proj_gemm<<<dim3(32, 6), 256, 0, stream>>>(CTX, Wob, bo, out);
}